// Round 14
// baseline (139.859 us; speedup 1.0000x reference)
//
#include <hip/hip_runtime.h>
#include <math.h>

#define NQ 12
#define TPB 512

// R24: 8 SAMPLES/CU VIA TIME-SHARED LDS. Audit of R2-R23: samples/CU was
// pinned at 4 in EVERY round (32KB exchange buffer/sample); SIMD issue
// ~17-25%, DS ~30%, no pipe saturated, wall invariant ~33us. The only
// untested lever is independent work per CU. Design: TPB=512, two 4-wave
// TEAMS per block, each running the VERIFIED R2/R16 single-sample pipeline
// on its own sample, sharing one S[4096] through alternating barrier-
// delimited windows; the schedule overlaps team A's exchange with team B's
// gate math. LDS/block ~34KB -> 4 blocks/CU x 2 samples = 8 samples/CU,
// 32 waves/CU (VGPR<=64 required; R16's identical code shapes = 64).
// All barriers TOP-LEVEL (never inside team-divergent code).
//
// Amp index j (12 bits), qubit q <-> j bit 11-q. Register layouts
// (tt = within-team thread 0..255, r = reg index 4 bits):
//   A: j = (r<<8)|tt                   r = j[11:8] = qubits 0..3
//   B: j = (tt[7:4]<<8)|(r<<4)|tt[3:0] r = j[7:4]  = qubits 4..7
//   C: j = (tt<<4)|r                   r = j[3:0]  = qubits 8..11
// B,C share wave bits j[11:10] -> X1/X5 are wave-local (CFENCE only).
// Swizzle sg(j) = (j&~15)|((j^(j>>4)^(j>>8))&15); kC=(tt^(tt>>4))&15:
//   sg(J_A(r)) = VA ^ 257r,  VA = (tt&0xF0)|kC
//   sg(J_B(r)) = VB ^ 17r,   VB = ((tt>>4)<<8)|kC
//   sg(J_C(r)) = VC ^ r,     VC = (tt<<4)|kC
//   sg(P(j))   = Ft ^ G(r<<8), Ft per-thread, G const-folded
//
// Window schedule (each | = __syncthreads; a=team0 b=team1):
//  W1 a:X1 | W2 b:X1,a:M4 | W3 a:stB,b:M4 | W4 a:rdA | W5 b:stB,a:M0 |
//  W6 b:rdA | W7 a:ringSt,b:M0 | W8 a:ringRd | W9 b:ringSt,a:RY0 |
//  W10 b:ringRd | W11 a:stA,b:RY0 | W12 a:rdB | W13 b:stA,a:RY4 |
//  W14 b:rdB | W15 a:X5,b:RY4 | W16 b:X5,a:{RY8,WHT,red} |
//  W17 b:{RY8,WHT,red} | out.
// Every store-window is preceded (via sync) by completion of the prior
// occupant's reads; teams touch disjoint red/gm/coI arrays.
//
// Circuit (algebra verified R2-R10): init(C) = L0 RX product state with
// ring0 FOLDED via inverse perm; fused M_q = RX(L1)*RZ(L0)*RY(L0) as raw
// SU(2) [[a,-conj b],[b,conj a]] via VOP3P op_sel/neg (8 pk ops/pair);
// ring1 scatter; L1 RY (final RZ dropped); <Z_q> via partial reg-WHT +
// 6-stage lane-WHT butterfly.

__device__ __forceinline__ float2 pk_mul(float2 a, float2 b) {
    float2 d;
    asm("v_pk_mul_f32 %0, %1, %2" : "=v"(d) : "v"(a), "v"(b));
    return d;
}
__device__ __forceinline__ float2 pk_fma(float2 a, float2 b, float2 c) {
    float2 d;
    asm("v_pk_fma_f32 %0, %1, %2, %3" : "=v"(d) : "v"(a), "v"(b), "v"(c));
    return d;
}
// d.lo = a.hi*b.lo + c.lo ; d.hi = a.lo*b.hi + c.hi   (x<->y swap of a)
__device__ __forceinline__ float2 pk_fma_sw0(float2 a, float2 b, float2 c) {
    float2 d;
    asm("v_pk_fma_f32 %0, %1, %2, %3 op_sel:[1,0,0] op_sel_hi:[0,1,1]"
        : "=v"(d) : "v"(a), "v"(b), "v"(c));
    return d;
}
// d = a*(-b) + c
__device__ __forceinline__ float2 pk_fma_n1(float2 a, float2 b, float2 c) {
    float2 d;
    asm("v_pk_fma_f32 %0, %1, %2, %3 neg_lo:[0,1,0] neg_hi:[0,1,0]"
        : "=v"(d) : "v"(a), "v"(b), "v"(c));
    return d;
}
// d.lo = a.hi*(-b.lo) + c.lo ; d.hi = a.lo*(-b.hi) + c.hi
__device__ __forceinline__ float2 pk_fma_sw0n1(float2 a, float2 b, float2 c) {
    float2 d;
    asm("v_pk_fma_f32 %0, %1, %2, %3 op_sel:[1,0,0] op_sel_hi:[0,1,1] "
        "neg_lo:[0,1,0] neg_hi:[0,1,0]"
        : "=v"(d) : "v"(a), "v"(b), "v"(c));
    return d;
}

// variadic: commas inside the body are re-joined by __VA_ARGS__
#define FOR_PAIRS4(RB, ...) do {                                      \
    const int msk_ = 1 << (RB);                                       \
    _Pragma("unroll")                                                 \
    for (int h_ = 0; h_ < 8; ++h_) {                                  \
        const int i0 = ((h_ & ~(msk_ - 1)) << 1) | (h_ & (msk_ - 1)); \
        const int i1 = i0 | msk_;                                     \
        __VA_ARGS__;                                                  \
    } } while (0)

// strength-reduced swizzled addresses (VA/VB/VC in scope)
#define ADDR_A(r) (VA ^ (257 * (r)))
#define ADDR_B(r) (VB ^ (17 * (r)))
#define ADDR_C(r) (VC ^ (r))

// compiler-only fence for the barrier-less wave-local store->load aliasing
#define CFENCE asm volatile("" ::: "memory")

#define ST16(AX) do { _Pragma("unroll")                               \
    for (int r_ = 0; r_ < 16; ++r_) S[AX(r_)] = v[r_]; } while (0)
#define RD16(AX) do { _Pragma("unroll")                               \
    for (int r_ = 0; r_ < 16; ++r_) v[r_] = S[AX(r_)]; } while (0)

#define RING_ST do { _Pragma("unroll")                                      \
    for (int r_ = 0; r_ < 16; ++r_) {                                       \
        const int jr_ = r_ << 8;                                            \
        int yr_ = jr_ ^ (jr_ >> 1); yr_ ^= yr_ >> 2; yr_ ^= yr_ >> 4;       \
        yr_ ^= yr_ >> 8;                                                    \
        const int pr_ = (yr_ & 0x7FF) |                                     \
                        (((__popc(jr_) ^ (jr_ >> 11)) & 1) << 11);          \
        const int Gr_ = (pr_ & ~15) |                                       \
                        ((pr_ ^ (pr_ >> 4) ^ (pr_ >> 8)) & 15);             \
        S[Ft ^ Gr_] = v[r_];                                                \
    } } while (0)

// SU(2) gate [[a, -conj(b)], [b, conj(a)]]; gmT[q] = {(ax,ax),(-ay,ay),
// (bx,bx),(-by,by)} broadcast LDS reads (R2/R16-verified, 64-VGPR-clean)
#define M_GATE(q, RB) do {                                                  \
        const float2 ar = gmT[q][0];                                        \
        const float2 ai = gmT[q][1];                                        \
        const float2 br = gmT[q][2];                                        \
        const float2 bi = gmT[q][3];                                        \
        FOR_PAIRS4(RB,                                                      \
            const float2 a0 = v[i0];                                        \
            const float2 a1 = v[i1];                                        \
            float2 n0 = pk_mul(a0, ar);                                     \
            n0 = pk_fma_sw0(a0, ai, n0);                                    \
            n0 = pk_fma_n1(a1, br, n0);                                     \
            n0 = pk_fma_sw0(a1, bi, n0);                                    \
            float2 n1 = pk_mul(a0, br);                                     \
            n1 = pk_fma_sw0(a0, bi, n1);                                    \
            n1 = pk_fma(a1, ar, n1);                                        \
            n1 = pk_fma_sw0n1(a1, ai, n1);                                  \
            v[i0] = n0; v[i1] = n1;                                         \
        );                                                                  \
    } while (0)

// gy[q] = { (c,c), (s,s) } (sample-independent)
#define RY_GATE(q, RB) do {                                                 \
        const float2 c2 = gy[q][0];                                         \
        const float2 s2 = gy[q][1];                                         \
        FOR_PAIRS4(RB,                                                      \
            float2 n0 = pk_fma_n1(v[i1], s2, pk_mul(v[i0], c2));            \
            float2 n1 = pk_fma(v[i0], s2, pk_mul(v[i1], c2));               \
            v[i0] = n0; v[i1] = n1;                                         \
        );                                                                  \
    } while (0)

#define M_PHASE(QB)  do { _Pragma("unroll")                                 \
    for (int d_ = 0; d_ < 4; ++d_) M_GATE((QB) + d_, 3 - d_); } while (0)
#define RY_PHASE(QB) do { _Pragma("unroll")                                 \
    for (int d_ = 0; d_ < 4; ++d_) RY_GATE((QB) + d_, 3 - d_); } while (0)

__global__ __launch_bounds__(TPB, 8) void vqc_kernel(
    const float* __restrict__ x,    // [B, 12]
    const float* __restrict__ th,   // [2, 12, 2]
    const float* __restrict__ lm,   // [2, 12]
    float* __restrict__ out)        // [B, 12]
{
    __shared__ float2 S[4096];          // time-shared between teams
    __shared__ float2 gm[2][12][4];     // fused M gate, per team
    __shared__ float2 gy[12][2];        // L1 RY (sample-independent)
    __shared__ float2 coI[2][12];       // L0 RX half-angle, per team
    __shared__ float red[2][4 * 12];

    const int b    = blockIdx.x;        // samples 2b (team0), 2b+1 (team1)
    const int t    = threadIdx.x;
    const int team = t >> 8;            // wave-uniform
    const int tt   = t & 255;
    const int l    = t & 63;
    const int w    = tt >> 6;
    const int smp  = 2 * b + team;

    const float2 (*gmT)[4] = gm[team];

    // strength-reduced address bases (within-team)
    const int kC = (tt ^ (tt >> 4)) & 15;
    const int VA = (tt & 0xF0) | kC;
    const int VB = ((tt >> 4) << 8) | kC;
    const int VC = (tt << 4) | kC;
    int Ft;
    {
        int yt = tt ^ (tt >> 1); yt ^= yt >> 2; yt ^= yt >> 4; yt ^= yt >> 8;
        int pt = (yt & 0x7FF) | ((__popc(tt) & 1) << 11);
        Ft = (pt & ~15) | ((pt ^ (pt >> 4) ^ (pt >> 8)) & 15);
    }

    // ---- coefficient precompute (each team computes its own sample) ----
    if (tt < 12) {
        float h = 0.5f * lm[tt] * x[smp * NQ + tt];
        float c, s; __sincosf(h, &s, &c);
        coI[team][tt] = make_float2(c, s);
    } else if (tt < 24) {
        if (team == 0) {                // gy sample-independent: one writer
            int q = tt - 12;
            float h = 0.5f * th[24 + 2 * q];
            float c, s; __sincosf(h, &s, &c);
            gy[q][0] = make_float2(c, c);
            gy[q][1] = make_float2(s, s);
        }
    } else if (tt < 36) {
        int q = tt - 24;
        float ha = 0.5f * lm[12 + q] * x[smp * NQ + q];  // L1 RX half
        float hy = 0.5f * th[2 * q];                     // L0 RY half
        float hz = 0.5f * th[2 * q + 1];                 // L0 RZ half
        float ca, sa, cy, sy, cz, sz;
        __sincosf(ha, &sa, &ca);
        __sincosf(hy, &sy, &cy);
        __sincosf(hz, &sz, &cz);
        // M = RX(a) RZ(z) RY(y): alpha = M00, beta = M10 (R9-verified)
        float ax = ca*cy*cz + sa*sy*sz;
        float ay = -(ca*cy*sz + sa*sy*cz);
        float bx = ca*sy*cz - sa*cy*sz;
        float by = ca*sy*sz - sa*cy*cz;
        gm[team][q][0] = make_float2(ax, ax);
        gm[team][q][1] = make_float2(-ay, ay);
        gm[team][q][2] = make_float2(bx, bx);
        gm[team][q][3] = make_float2(-by, by);
    }
    __syncthreads();                                   // B1

    float2 v[16];

    // ---- init in layout C: L0 RX product state, ring0 folded ----
    // (R10-verified) bit relations on tt, per team's coI
    {
        const float2* coIs = coI[team];
        const int g = (tt ^ (tt >> 1)) & 0x3F;
        float Pt = 1.0f;
#pragma unroll
        for (int m = 0; m < 6; ++m) {
            float2 cs = coIs[7 - m];
            Pt *= ((g >> m) & 1) ? cs.y : cs.x;
        }
        const int ct = __popc(g);
        const int t0 = tt & 1, t7 = (tt >> 7) & 1;
        const int e1 = ((tt >> 6) ^ (tt >> 7)) & 1;
        float2 q11 = coIs[11], q10 = coIs[10], q9 = coIs[9],
               q8 = coIs[8], q1 = coIs[1], q0 = coIs[0];
        const float u8  = t0 ? q8.y : q8.x;     // qubit 8, key t0^r3
        const float u8n = t0 ? q8.x : q8.y;
        const float u1  = e1 ? q1.y : q1.x;     // qubit 1, key e1^r0
        const float u1n = e1 ? q1.x : q1.y;
        const float u0  = t7 ? q0.y : q0.x;     // qubit 0, key t7^r0
        const float u0n = t7 ? q0.x : q0.y;
#pragma unroll
        for (int r = 0; r < 16; ++r) {
            const int r0 = r & 1, r1 = (r >> 1) & 1, r2 = (r >> 2) & 1,
                      r3 = (r >> 3) & 1;
            const int b11 = r0 ^ r1, b10 = r1 ^ r2, b9 = r2 ^ r3;
            float m = Pt * (b11 ? q11.y : q11.x) * (b10 ? q10.y : q10.x)
                         * (b9 ? q9.y : q9.x) * (r3 ? u8n : u8)
                         * (r0 ? u1n : u1) * (r0 ? u0n : u0);
            int k = (ct + b11 + b10 + b9 + (r3 ^ t0) + (r0 ^ e1) + (r0 ^ t7)) & 3;
            v[r].x = (k == 0) ? m : ((k == 2) ? -m : 0.0f);
            v[r].y = (k == 3) ? m : ((k == 1) ? -m : 0.0f);
        }
    }

    M_PHASE(8);                              // both teams: qubits 8..11 (C)

    // ---- windowed pipeline (see header schedule) ----
    if (team == 0) { ST16(ADDR_C); CFENCE; RD16(ADDR_B); }       // W1 a:X1
    __syncthreads();
    if (team == 1) { ST16(ADDR_C); CFENCE; RD16(ADDR_B); }       // W2 b:X1
    else           { M_PHASE(4); }                               //    a:M4
    __syncthreads();
    if (team == 0) { ST16(ADDR_B); }                             // W3 a:stB
    else           { M_PHASE(4); }                               //    b:M4
    __syncthreads();
    if (team == 0) { RD16(ADDR_A); }                             // W4 a:rdA
    __syncthreads();
    if (team == 1) { ST16(ADDR_B); }                             // W5 b:stB
    else           { M_PHASE(0); }                               //    a:M0
    __syncthreads();
    if (team == 1) { RD16(ADDR_A); }                             // W6 b:rdA
    __syncthreads();
    if (team == 0) { RING_ST; }                                  // W7 a:ring
    else           { M_PHASE(0); }                               //    b:M0
    __syncthreads();
    if (team == 0) { RD16(ADDR_A); }                             // W8 a:rd
    __syncthreads();
    if (team == 1) { RING_ST; }                                  // W9 b:ring
    else           { RY_PHASE(0); }                              //    a:RY0
    __syncthreads();
    if (team == 1) { RD16(ADDR_A); }                             // W10 b:rd
    __syncthreads();
    if (team == 0) { ST16(ADDR_A); }                             // W11 a:stA
    else           { RY_PHASE(0); }                              //    b:RY0
    __syncthreads();
    if (team == 0) { RD16(ADDR_B); }                             // W12 a:rdB
    __syncthreads();
    if (team == 1) { ST16(ADDR_A); }                             // W13 b:stA
    else           { RY_PHASE(4); }                              //    a:RY4
    __syncthreads();
    if (team == 1) { RD16(ADDR_B); }                             // W14 b:rdB
    __syncthreads();
    if (team == 0) { ST16(ADDR_B); CFENCE; RD16(ADDR_C); }       // W15 a:X5
    else           { RY_PHASE(4); }                              //    b:RY4
    __syncthreads();

    // W16: b:X5 ; a: RY8 + measure-reduce.  W17: b: RY8 + measure-reduce.
    if (team == 1) { ST16(ADDR_B); CFENCE; RD16(ADDR_C); }
    RY_PHASE(8);        // a: W16 (after its X5 in W15); b: W16/17 after X5

    // ---- measurement in C (per team; red arrays disjoint) ----
    float p[16];
#pragma unroll
    for (int r = 0; r < 16; ++r)
        p[r] = fmaf(v[r].x, v[r].x, v[r].y * v[r].y);
    float sA[8], dA[8];
#pragma unroll
    for (int k = 0; k < 8; ++k) {
        sA[k] = p[2 * k] + p[2 * k + 1];
        dA[k] = p[2 * k] - p[2 * k + 1];
    }
    float z11 = ((dA[0] + dA[1]) + (dA[2] + dA[3]))
              + ((dA[4] + dA[5]) + (dA[6] + dA[7]));
    float sC[4], dC[4];
#pragma unroll
    for (int k = 0; k < 4; ++k) {
        sC[k] = sA[2 * k] + sA[2 * k + 1];
        dC[k] = sA[2 * k] - sA[2 * k + 1];
    }
    float z10 = (dC[0] + dC[1]) + (dC[2] + dC[3]);
    float e0 = sC[0] + sC[1], f0 = sC[0] - sC[1];
    float e1s = sC[2] + sC[3], f1 = sC[2] - sC[3];
    float vals[5];
    vals[0] = e0 + e1s;               // ptot
    vals[1] = e0 - e1s;               // z8  (r bit3)
    vals[2] = f0 + f1;                // z9  (r bit2)
    vals[3] = z10;                    // z10 (r bit1)
    vals[4] = z11;                    // z11 (r bit0)

    // 6-stage WHT butterfly: lane L ends with sum_l (-1)^{popc(L&l)} x_l
#pragma unroll
    for (int k = 0; k < 6; ++k) {
        const float sgn = ((l >> k) & 1) ? -1.f : 1.f;
#pragma unroll
        for (int m = 0; m < 5; ++m) {
            float tmp = __shfl_xor(vals[m], 1 << k, 64);
            vals[m] = fmaf(sgn, vals[m], tmp);
        }
    }
    if (l == 0) {                     // wave totals
        red[team][w * 12 + 0]  = vals[0];   // ptot (for qubits 0,1)
        red[team][w * 12 + 8]  = vals[1];
        red[team][w * 12 + 9]  = vals[2];
        red[team][w * 12 + 10] = vals[3];
        red[team][w * 12 + 11] = vals[4];
    } else if (__popc(l) == 1) {      // lane-bit sums: qubits 2..7
        int q = 8 - __ffs(l);         // l=1<<k -> q = 7-k
        red[team][w * 12 + q] = vals[0];
    }
    __syncthreads();                  // SR
    if (tt < NQ) {
        float acc = 0.f;
#pragma unroll
        for (int ww = 0; ww < 4; ++ww) {
            if (tt < 2) {
                float pv = red[team][ww * 12 + 0];
                acc += ((ww >> (1 - tt)) & 1) ? -pv : pv;
            } else {
                acc += red[team][ww * 12 + tt];
            }
        }
        out[smp * NQ + tt] = acc;
    }
}

extern "C" void kernel_launch(void* const* d_in, const int* in_sizes, int n_in,
                              void* d_out, int out_size, void* d_ws, size_t ws_size,
                              hipStream_t stream) {
    const int B = in_sizes[0] / NQ;  // 1024
    vqc_kernel<<<B / 2, TPB, 0, stream>>>((const float*)d_in[0],
                                          (const float*)d_in[1],
                                          (const float*)d_in[2],
                                          (float*)d_out);
}

// Round 15
// 74.777 us; speedup vs baseline: 1.8704x; 1.8704x over previous
//
#include <hip/hip_runtime.h>
#include <math.h>

#define NQ 12
#define TPB 512

// R25: R24 RETRY WITH CORRECT LAUNCH_BOUNDS SEMANTICS. R24's counters
// (VGPR_Count=32, 74MB FETCH + 133MB WRITE scratch traffic) decode as:
// HIP __launch_bounds__ 2nd arg = min BLOCKS per CU (CUDA semantics):
// (512,8) -> 64 waves/CU -> 16/SIMD -> 32-reg cap -> total spill. The
// 8-samples/CU experiment was never tested. Correct cap: (512,4) ->
// 4 blocks x 8 waves = 32 waves/CU = 8/SIMD -> 64-VGPR cap; R16 measured
// this exact inner code at EXACTLY 64 VGPRs, so it fits. LDS 34.3KB x 4
// = 137KB < 160 OK. Team schedule correctness verified in R24 (passed,
// absmax 2e-3). Everything else byte-identical to R24.
//
// Amp index j (12 bits), qubit q <-> j bit 11-q. Register layouts
// (tt = within-team thread 0..255, r = reg index 4 bits):
//   A: j = (r<<8)|tt                   r = j[11:8] = qubits 0..3
//   B: j = (tt[7:4]<<8)|(r<<4)|tt[3:0] r = j[7:4]  = qubits 4..7
//   C: j = (tt<<4)|r                   r = j[3:0]  = qubits 8..11
// B,C share wave bits j[11:10] -> X1/X5 are wave-local (CFENCE only).
// Swizzle sg(j) = (j&~15)|((j^(j>>4)^(j>>8))&15); kC=(tt^(tt>>4))&15:
//   sg(J_A(r)) = VA ^ 257r,  VA = (tt&0xF0)|kC
//   sg(J_B(r)) = VB ^ 17r,   VB = ((tt>>4)<<8)|kC
//   sg(J_C(r)) = VC ^ r,     VC = (tt<<4)|kC
//   sg(P(j))   = Ft ^ G(r<<8), Ft per-thread, G const-folded
//
// Window schedule (each | = __syncthreads; a=team0 b=team1):
//  W1 a:X1 | W2 b:X1,a:M4 | W3 a:stB,b:M4 | W4 a:rdA | W5 b:stB,a:M0 |
//  W6 b:rdA | W7 a:ringSt,b:M0 | W8 a:ringRd | W9 b:ringSt,a:RY0 |
//  W10 b:ringRd | W11 a:stA,b:RY0 | W12 a:rdB | W13 b:stA,a:RY4 |
//  W14 b:rdB | W15 a:X5,b:RY4 | W16 b:X5,a:{RY8,WHT,red} |
//  W17 b:{RY8,WHT,red} | out.
//
// Circuit (algebra verified R2-R10): init(C) = L0 RX product state with
// ring0 FOLDED via inverse perm; fused M_q = RX(L1)*RZ(L0)*RY(L0) as raw
// SU(2) [[a,-conj b],[b,conj a]] via VOP3P op_sel/neg (8 pk ops/pair);
// ring1 scatter; L1 RY (final RZ dropped); <Z_q> via partial reg-WHT +
// 6-stage lane-WHT butterfly.

__device__ __forceinline__ float2 pk_mul(float2 a, float2 b) {
    float2 d;
    asm("v_pk_mul_f32 %0, %1, %2" : "=v"(d) : "v"(a), "v"(b));
    return d;
}
__device__ __forceinline__ float2 pk_fma(float2 a, float2 b, float2 c) {
    float2 d;
    asm("v_pk_fma_f32 %0, %1, %2, %3" : "=v"(d) : "v"(a), "v"(b), "v"(c));
    return d;
}
// d.lo = a.hi*b.lo + c.lo ; d.hi = a.lo*b.hi + c.hi   (x<->y swap of a)
__device__ __forceinline__ float2 pk_fma_sw0(float2 a, float2 b, float2 c) {
    float2 d;
    asm("v_pk_fma_f32 %0, %1, %2, %3 op_sel:[1,0,0] op_sel_hi:[0,1,1]"
        : "=v"(d) : "v"(a), "v"(b), "v"(c));
    return d;
}
// d = a*(-b) + c
__device__ __forceinline__ float2 pk_fma_n1(float2 a, float2 b, float2 c) {
    float2 d;
    asm("v_pk_fma_f32 %0, %1, %2, %3 neg_lo:[0,1,0] neg_hi:[0,1,0]"
        : "=v"(d) : "v"(a), "v"(b), "v"(c));
    return d;
}
// d.lo = a.hi*(-b.lo) + c.lo ; d.hi = a.lo*(-b.hi) + c.hi
__device__ __forceinline__ float2 pk_fma_sw0n1(float2 a, float2 b, float2 c) {
    float2 d;
    asm("v_pk_fma_f32 %0, %1, %2, %3 op_sel:[1,0,0] op_sel_hi:[0,1,1] "
        "neg_lo:[0,1,0] neg_hi:[0,1,0]"
        : "=v"(d) : "v"(a), "v"(b), "v"(c));
    return d;
}

// variadic: commas inside the body are re-joined by __VA_ARGS__
#define FOR_PAIRS4(RB, ...) do {                                      \
    const int msk_ = 1 << (RB);                                       \
    _Pragma("unroll")                                                 \
    for (int h_ = 0; h_ < 8; ++h_) {                                  \
        const int i0 = ((h_ & ~(msk_ - 1)) << 1) | (h_ & (msk_ - 1)); \
        const int i1 = i0 | msk_;                                     \
        __VA_ARGS__;                                                  \
    } } while (0)

// strength-reduced swizzled addresses (VA/VB/VC in scope)
#define ADDR_A(r) (VA ^ (257 * (r)))
#define ADDR_B(r) (VB ^ (17 * (r)))
#define ADDR_C(r) (VC ^ (r))

// compiler-only fence for the barrier-less wave-local store->load aliasing
#define CFENCE asm volatile("" ::: "memory")

#define ST16(AX) do { _Pragma("unroll")                               \
    for (int r_ = 0; r_ < 16; ++r_) S[AX(r_)] = v[r_]; } while (0)
#define RD16(AX) do { _Pragma("unroll")                               \
    for (int r_ = 0; r_ < 16; ++r_) v[r_] = S[AX(r_)]; } while (0)

#define RING_ST do { _Pragma("unroll")                                      \
    for (int r_ = 0; r_ < 16; ++r_) {                                       \
        const int jr_ = r_ << 8;                                            \
        int yr_ = jr_ ^ (jr_ >> 1); yr_ ^= yr_ >> 2; yr_ ^= yr_ >> 4;       \
        yr_ ^= yr_ >> 8;                                                    \
        const int pr_ = (yr_ & 0x7FF) |                                     \
                        (((__popc(jr_) ^ (jr_ >> 11)) & 1) << 11);          \
        const int Gr_ = (pr_ & ~15) |                                       \
                        ((pr_ ^ (pr_ >> 4) ^ (pr_ >> 8)) & 15);             \
        S[Ft ^ Gr_] = v[r_];                                                \
    } } while (0)

// SU(2) gate [[a, -conj(b)], [b, conj(a)]]; gmT[q] = {(ax,ax),(-ay,ay),
// (bx,bx),(-by,by)} broadcast LDS reads (R2/R16-verified, 64-VGPR-clean)
#define M_GATE(q, RB) do {                                                  \
        const float2 ar = gmT[q][0];                                        \
        const float2 ai = gmT[q][1];                                        \
        const float2 br = gmT[q][2];                                        \
        const float2 bi = gmT[q][3];                                        \
        FOR_PAIRS4(RB,                                                      \
            const float2 a0 = v[i0];                                        \
            const float2 a1 = v[i1];                                        \
            float2 n0 = pk_mul(a0, ar);                                     \
            n0 = pk_fma_sw0(a0, ai, n0);                                    \
            n0 = pk_fma_n1(a1, br, n0);                                     \
            n0 = pk_fma_sw0(a1, bi, n0);                                    \
            float2 n1 = pk_mul(a0, br);                                     \
            n1 = pk_fma_sw0(a0, bi, n1);                                    \
            n1 = pk_fma(a1, ar, n1);                                        \
            n1 = pk_fma_sw0n1(a1, ai, n1);                                  \
            v[i0] = n0; v[i1] = n1;                                         \
        );                                                                  \
    } while (0)

// gy[q] = { (c,c), (s,s) } (sample-independent)
#define RY_GATE(q, RB) do {                                                 \
        const float2 c2 = gy[q][0];                                         \
        const float2 s2 = gy[q][1];                                         \
        FOR_PAIRS4(RB,                                                      \
            float2 n0 = pk_fma_n1(v[i1], s2, pk_mul(v[i0], c2));            \
            float2 n1 = pk_fma(v[i0], s2, pk_mul(v[i1], c2));               \
            v[i0] = n0; v[i1] = n1;                                         \
        );                                                                  \
    } while (0)

#define M_PHASE(QB)  do { _Pragma("unroll")                                 \
    for (int d_ = 0; d_ < 4; ++d_) M_GATE((QB) + d_, 3 - d_); } while (0)
#define RY_PHASE(QB) do { _Pragma("unroll")                                 \
    for (int d_ = 0; d_ < 4; ++d_) RY_GATE((QB) + d_, 3 - d_); } while (0)

__global__ __launch_bounds__(TPB, 4) void vqc_kernel(
    const float* __restrict__ x,    // [B, 12]
    const float* __restrict__ th,   // [2, 12, 2]
    const float* __restrict__ lm,   // [2, 12]
    float* __restrict__ out)        // [B, 12]
{
    __shared__ float2 S[4096];          // time-shared between teams
    __shared__ float2 gm[2][12][4];     // fused M gate, per team
    __shared__ float2 gy[12][2];        // L1 RY (sample-independent)
    __shared__ float2 coI[2][12];       // L0 RX half-angle, per team
    __shared__ float red[2][4 * 12];

    const int b    = blockIdx.x;        // samples 2b (team0), 2b+1 (team1)
    const int t    = threadIdx.x;
    const int team = t >> 8;            // wave-uniform
    const int tt   = t & 255;
    const int l    = t & 63;
    const int w    = tt >> 6;
    const int smp  = 2 * b + team;

    const float2 (*gmT)[4] = gm[team];

    // strength-reduced address bases (within-team)
    const int kC = (tt ^ (tt >> 4)) & 15;
    const int VA = (tt & 0xF0) | kC;
    const int VB = ((tt >> 4) << 8) | kC;
    const int VC = (tt << 4) | kC;
    int Ft;
    {
        int yt = tt ^ (tt >> 1); yt ^= yt >> 2; yt ^= yt >> 4; yt ^= yt >> 8;
        int pt = (yt & 0x7FF) | ((__popc(tt) & 1) << 11);
        Ft = (pt & ~15) | ((pt ^ (pt >> 4) ^ (pt >> 8)) & 15);
    }

    // ---- coefficient precompute (each team computes its own sample) ----
    if (tt < 12) {
        float h = 0.5f * lm[tt] * x[smp * NQ + tt];
        float c, s; __sincosf(h, &s, &c);
        coI[team][tt] = make_float2(c, s);
    } else if (tt < 24) {
        if (team == 0) {                // gy sample-independent: one writer
            int q = tt - 12;
            float h = 0.5f * th[24 + 2 * q];
            float c, s; __sincosf(h, &s, &c);
            gy[q][0] = make_float2(c, c);
            gy[q][1] = make_float2(s, s);
        }
    } else if (tt < 36) {
        int q = tt - 24;
        float ha = 0.5f * lm[12 + q] * x[smp * NQ + q];  // L1 RX half
        float hy = 0.5f * th[2 * q];                     // L0 RY half
        float hz = 0.5f * th[2 * q + 1];                 // L0 RZ half
        float ca, sa, cy, sy, cz, sz;
        __sincosf(ha, &sa, &ca);
        __sincosf(hy, &sy, &cy);
        __sincosf(hz, &sz, &cz);
        // M = RX(a) RZ(z) RY(y): alpha = M00, beta = M10 (R9-verified)
        float ax = ca*cy*cz + sa*sy*sz;
        float ay = -(ca*cy*sz + sa*sy*cz);
        float bx = ca*sy*cz - sa*cy*sz;
        float by = ca*sy*sz - sa*cy*cz;
        gm[team][q][0] = make_float2(ax, ax);
        gm[team][q][1] = make_float2(-ay, ay);
        gm[team][q][2] = make_float2(bx, bx);
        gm[team][q][3] = make_float2(-by, by);
    }
    __syncthreads();                                   // B1

    float2 v[16];

    // ---- init in layout C: L0 RX product state, ring0 folded ----
    // (R10-verified) bit relations on tt, per team's coI
    {
        const float2* coIs = coI[team];
        const int g = (tt ^ (tt >> 1)) & 0x3F;
        float Pt = 1.0f;
#pragma unroll
        for (int m = 0; m < 6; ++m) {
            float2 cs = coIs[7 - m];
            Pt *= ((g >> m) & 1) ? cs.y : cs.x;
        }
        const int ct = __popc(g);
        const int t0 = tt & 1, t7 = (tt >> 7) & 1;
        const int e1 = ((tt >> 6) ^ (tt >> 7)) & 1;
        float2 q11 = coIs[11], q10 = coIs[10], q9 = coIs[9],
               q8 = coIs[8], q1 = coIs[1], q0 = coIs[0];
        const float u8  = t0 ? q8.y : q8.x;     // qubit 8, key t0^r3
        const float u8n = t0 ? q8.x : q8.y;
        const float u1  = e1 ? q1.y : q1.x;     // qubit 1, key e1^r0
        const float u1n = e1 ? q1.x : q1.y;
        const float u0  = t7 ? q0.y : q0.x;     // qubit 0, key t7^r0
        const float u0n = t7 ? q0.x : q0.y;
#pragma unroll
        for (int r = 0; r < 16; ++r) {
            const int r0 = r & 1, r1 = (r >> 1) & 1, r2 = (r >> 2) & 1,
                      r3 = (r >> 3) & 1;
            const int b11 = r0 ^ r1, b10 = r1 ^ r2, b9 = r2 ^ r3;
            float m = Pt * (b11 ? q11.y : q11.x) * (b10 ? q10.y : q10.x)
                         * (b9 ? q9.y : q9.x) * (r3 ? u8n : u8)
                         * (r0 ? u1n : u1) * (r0 ? u0n : u0);
            int k = (ct + b11 + b10 + b9 + (r3 ^ t0) + (r0 ^ e1) + (r0 ^ t7)) & 3;
            v[r].x = (k == 0) ? m : ((k == 2) ? -m : 0.0f);
            v[r].y = (k == 3) ? m : ((k == 1) ? -m : 0.0f);
        }
    }

    M_PHASE(8);                              // both teams: qubits 8..11 (C)

    // ---- windowed pipeline (see header schedule) ----
    if (team == 0) { ST16(ADDR_C); CFENCE; RD16(ADDR_B); }       // W1 a:X1
    __syncthreads();
    if (team == 1) { ST16(ADDR_C); CFENCE; RD16(ADDR_B); }       // W2 b:X1
    else           { M_PHASE(4); }                               //    a:M4
    __syncthreads();
    if (team == 0) { ST16(ADDR_B); }                             // W3 a:stB
    else           { M_PHASE(4); }                               //    b:M4
    __syncthreads();
    if (team == 0) { RD16(ADDR_A); }                             // W4 a:rdA
    __syncthreads();
    if (team == 1) { ST16(ADDR_B); }                             // W5 b:stB
    else           { M_PHASE(0); }                               //    a:M0
    __syncthreads();
    if (team == 1) { RD16(ADDR_A); }                             // W6 b:rdA
    __syncthreads();
    if (team == 0) { RING_ST; }                                  // W7 a:ring
    else           { M_PHASE(0); }                               //    b:M0
    __syncthreads();
    if (team == 0) { RD16(ADDR_A); }                             // W8 a:rd
    __syncthreads();
    if (team == 1) { RING_ST; }                                  // W9 b:ring
    else           { RY_PHASE(0); }                              //    a:RY0
    __syncthreads();
    if (team == 1) { RD16(ADDR_A); }                             // W10 b:rd
    __syncthreads();
    if (team == 0) { ST16(ADDR_A); }                             // W11 a:stA
    else           { RY_PHASE(0); }                              //    b:RY0
    __syncthreads();
    if (team == 0) { RD16(ADDR_B); }                             // W12 a:rdB
    __syncthreads();
    if (team == 1) { ST16(ADDR_A); }                             // W13 b:stA
    else           { RY_PHASE(4); }                              //    a:RY4
    __syncthreads();
    if (team == 1) { RD16(ADDR_B); }                             // W14 b:rdB
    __syncthreads();
    if (team == 0) { ST16(ADDR_B); CFENCE; RD16(ADDR_C); }       // W15 a:X5
    else           { RY_PHASE(4); }                              //    b:RY4
    __syncthreads();

    // W16: b:X5 ; a: RY8 + measure-reduce.  W17: b: RY8 + measure-reduce.
    if (team == 1) { ST16(ADDR_B); CFENCE; RD16(ADDR_C); }
    RY_PHASE(8);        // a: W16 (after its X5 in W15); b: W16/17 after X5

    // ---- measurement in C (per team; red arrays disjoint) ----
    float p[16];
#pragma unroll
    for (int r = 0; r < 16; ++r)
        p[r] = fmaf(v[r].x, v[r].x, v[r].y * v[r].y);
    float sA[8], dA[8];
#pragma unroll
    for (int k = 0; k < 8; ++k) {
        sA[k] = p[2 * k] + p[2 * k + 1];
        dA[k] = p[2 * k] - p[2 * k + 1];
    }
    float z11 = ((dA[0] + dA[1]) + (dA[2] + dA[3]))
              + ((dA[4] + dA[5]) + (dA[6] + dA[7]));
    float sC[4], dC[4];
#pragma unroll
    for (int k = 0; k < 4; ++k) {
        sC[k] = sA[2 * k] + sA[2 * k + 1];
        dC[k] = sA[2 * k] - sA[2 * k + 1];
    }
    float z10 = (dC[0] + dC[1]) + (dC[2] + dC[3]);
    float e0 = sC[0] + sC[1], f0 = sC[0] - sC[1];
    float e1s = sC[2] + sC[3], f1 = sC[2] - sC[3];
    float vals[5];
    vals[0] = e0 + e1s;               // ptot
    vals[1] = e0 - e1s;               // z8  (r bit3)
    vals[2] = f0 + f1;                // z9  (r bit2)
    vals[3] = z10;                    // z10 (r bit1)
    vals[4] = z11;                    // z11 (r bit0)

    // 6-stage WHT butterfly: lane L ends with sum_l (-1)^{popc(L&l)} x_l
#pragma unroll
    for (int k = 0; k < 6; ++k) {
        const float sgn = ((l >> k) & 1) ? -1.f : 1.f;
#pragma unroll
        for (int m = 0; m < 5; ++m) {
            float tmp = __shfl_xor(vals[m], 1 << k, 64);
            vals[m] = fmaf(sgn, vals[m], tmp);
        }
    }
    if (l == 0) {                     // wave totals
        red[team][w * 12 + 0]  = vals[0];   // ptot (for qubits 0,1)
        red[team][w * 12 + 8]  = vals[1];
        red[team][w * 12 + 9]  = vals[2];
        red[team][w * 12 + 10] = vals[3];
        red[team][w * 12 + 11] = vals[4];
    } else if (__popc(l) == 1) {      // lane-bit sums: qubits 2..7
        int q = 8 - __ffs(l);         // l=1<<k -> q = 7-k
        red[team][w * 12 + q] = vals[0];
    }
    __syncthreads();                  // SR
    if (tt < NQ) {
        float acc = 0.f;
#pragma unroll
        for (int ww = 0; ww < 4; ++ww) {
            if (tt < 2) {
                float pv = red[team][ww * 12 + 0];
                acc += ((ww >> (1 - tt)) & 1) ? -pv : pv;
            } else {
                acc += red[team][ww * 12 + tt];
            }
        }
        out[smp * NQ + tt] = acc;
    }
}

extern "C" void kernel_launch(void* const* d_in, const int* in_sizes, int n_in,
                              void* d_out, int out_size, void* d_ws, size_t ws_size,
                              hipStream_t stream) {
    const int B = in_sizes[0] / NQ;  // 1024
    vqc_kernel<<<B / 2, TPB, 0, stream>>>((const float*)d_in[0],
                                          (const float*)d_in[1],
                                          (const float*)d_in[2],
                                          (float*)d_out);
}

// Round 16
// 73.625 us; speedup vs baseline: 1.8996x; 1.0156x over previous
//
#include <hip/hip_runtime.h>
#include <math.h>

#define NQ 12
#define TPB 256

// R26: NATIVE PACKED-F32 GATES (no inline asm in the hot loop). Evidence:
// R20 asm-pk stream runs at CPI~10; R22 compiler-scheduled scalar ran 2x
// the ops in 1.27x the time (CPI~6.4) -> inline-asm statements are opaque,
// order-pinned units LLVM cannot schedule across; that un-fillable bubble
// structure was carried through EVERY variant since baseline. Fix: express
// gate math as ext_vector_type(2) float arithmetic -- the AMDGPU backend
// lowers <2 x float> mul/fma to v_pk_fma_f32 (gfx90a+ packed FP32), folds
// fneg into neg modifiers and the (-y,x) shuffle into op_sel, and the
// scheduler gets full freedom. Same ~8-10 pk ops/pair as R19, schedulable.
// Base = R23 (best verified: 72.28 total), PIN kept, all else identical.
//
// Amp index j (12 bits), qubit q <-> j bit 11-q. Register layouts
// (t = thread 0..255 gives 8 bits, r = reg index 4 bits):
//   A: j = (r<<8)|t                  r = j[11:8] = qubits 0..3
//   B: j = (t[7:4]<<8)|(r<<4)|t[3:0] r = j[7:4]  = qubits 4..7
//   C: j = (t<<4)|r                  r = j[3:0]  = qubits 8..11
// B,C share wave bits j[11:10] -> B<->C roundtrips wave-local.
// Swizzle sg(j) = (j&~15)|((j^(j>>4)^(j>>8))&15); with kC=(t^(t>>4))&15:
//   sg(J_A(r)) = VA ^ 257r,  VA = (t&0xF0)|kC
//   sg(J_B(r)) = VB ^ 17r,   VB = ((t>>4)<<8)|kC
//   sg(J_C(r)) = VC ^ r,     VC = (t<<4)|kC
//   sg(P(j))   = Ft ^ G(r<<8), Ft per-thread, G const-folded
//
// Gate algebra (matches R22's verified scalar formulas exactly):
//   v0s = (-y0, x0), v1s = (-y1, x1)
//   n0 = ax*v0 + ay*v0s - bx*v1 + by*v1s   (= a*v0 - conj(b)*v1)
//   n1 = bx*v0 + by*v0s + ax*v1 - ay*v1s   (= b*v0 + conj(a)*v1)
//   RY: n0 = cc*v0 - ss*v1 ; n1 = ss*v0 + cc*v1
//
// Circuit (algebra verified R2-R10): init(C) = L0 RX product state with
// ring0 FOLDED via inverse perm; fused M_q = RX(L1)*RZ(L0)*RY(L0); ring1
// scatter; L1 RY (final RZ dropped); <Z_q> via partial reg-WHT + 6-stage
// lane-WHT butterfly.

typedef float v2f __attribute__((ext_vector_type(2)));

// opaque register pin (R23): severs link to LDS source, forces VGPR
#define PIN(f2) asm("" : "+v"(f2))

// variadic: commas inside the body are re-joined by __VA_ARGS__
#define FOR_PAIRS4(RB, ...) do {                                      \
    const int msk_ = 1 << (RB);                                       \
    _Pragma("unroll")                                                 \
    for (int h_ = 0; h_ < 8; ++h_) {                                  \
        const int i0 = ((h_ & ~(msk_ - 1)) << 1) | (h_ & (msk_ - 1)); \
        const int i1 = i0 | msk_;                                     \
        __VA_ARGS__;                                                  \
    } } while (0)

// strength-reduced swizzled addresses (VA/VB/VC in scope)
#define ADDR_A(r) (VA ^ (257 * (r)))
#define ADDR_B(r) (VB ^ (17 * (r)))
#define ADDR_C(r) (VC ^ (r))

// compiler-only fence for the barrier-less wave-local store->load aliasing
#define CFENCE asm volatile("" ::: "memory")

// wave-local roundtrip (same-wave LDS ordering, no barrier)
#define LOCAL_X(AS, AD) do {                                          \
    _Pragma("unroll")                                                 \
    for (int r_ = 0; r_ < 16; ++r_) S[AS(r_)] = v[r_];                \
    CFENCE;                                                           \
    _Pragma("unroll")                                                 \
    for (int r_ = 0; r_ < 16; ++r_) v[r_] = S[AD(r_)];                \
  } while (0)

// SU(2) gate in native packed-f32 form (backend emits v_pk_fma_f32 with
// folded neg/op_sel; fully schedulable)
#define M_GATE(q, RB) do {                                            \
        const float ax = GA[q].x, ay = GA[q].y;                       \
        const float bx = GB[q].x, by = GB[q].y;                       \
        FOR_PAIRS4(RB,                                                \
            const v2f v0 = v[i0];                                     \
            const v2f v1 = v[i1];                                     \
            const v2f v0s = (v2f){-v0.y, v0.x};                       \
            const v2f v1s = (v2f){-v1.y, v1.x};                       \
            v[i0] = ax*v0 + ay*v0s - bx*v1 + by*v1s;                  \
            v[i1] = bx*v0 + by*v0s + ax*v1 - ay*v1s;                  \
        );                                                            \
    } while (0)

#define RY_GATE(q, RB) do {                                           \
        const float cc = GY[q].x, ss = GY[q].y;                       \
        FOR_PAIRS4(RB,                                                \
            const v2f v0 = v[i0];                                     \
            const v2f v1 = v[i1];                                     \
            v[i0] = cc*v0 - ss*v1;                                    \
            v[i1] = ss*v0 + cc*v1;                                    \
        );                                                            \
    } while (0)

// phase: gate qubit QB+d on r-bit 3-d (holds for A, B, C alike)
#define M_PHASE(QB)  do { _Pragma("unroll")                                 \
    for (int d_ = 0; d_ < 4; ++d_) M_GATE((QB) + d_, 3 - d_); } while (0)
#define RY_PHASE(QB) do { _Pragma("unroll")                                 \
    for (int d_ = 0; d_ < 4; ++d_) RY_GATE((QB) + d_, 3 - d_); } while (0)

__global__ __launch_bounds__(TPB, 2) void vqc_kernel(
    const float* __restrict__ x,    // [B, 12]
    const float* __restrict__ th,   // [2, 12, 2]
    const float* __restrict__ lm,   // [2, 12]
    float* __restrict__ out)        // [B, 12]
{
    __shared__ v2f S[4096];
    __shared__ v2f gmA[12];         // fused M gate: (ax, ay)
    __shared__ v2f gmB[12];         // fused M gate: (bx, by)
    __shared__ v2f gyS[12];         // L1 RY: (c, s)
    __shared__ v2f coI[12];         // L0 RX half-angle (c,s)
    __shared__ float red[4 * 12];

    const int b = blockIdx.x;
    const int t = threadIdx.x;
    const int l = t & 63;
    const int w = t >> 6;

    // strength-reduced address bases
    const int kC = (t ^ (t >> 4)) & 15;
    const int VA = (t & 0xF0) | kC;
    const int VB = ((t >> 4) << 8) | kC;
    const int VC = (t << 4) | kC;
    // ring per-thread part: Ft = sg(P-image of t) (GF(2)-linear split)
    int Ft;
    {
        int yt = t ^ (t >> 1); yt ^= yt >> 2; yt ^= yt >> 4; yt ^= yt >> 8;
        int pt = (yt & 0x7FF) | ((__popc(t) & 1) << 11);
        Ft = (pt & ~15) | ((pt ^ (pt >> 4) ^ (pt >> 8)) & 15);
    }

    // ---- cooperative coefficient precompute ----
    if (t < 12) {
        float h = 0.5f * lm[t] * x[b * NQ + t];
        float c, s; __sincosf(h, &s, &c);
        coI[t] = (v2f){c, s};
    } else if (t < 24) {
        int q = t - 12;
        float h = 0.5f * th[24 + 2 * q];
        float c, s; __sincosf(h, &s, &c);
        gyS[q] = (v2f){c, s};
    } else if (t < 36) {
        int q = t - 24;
        float ha = 0.5f * lm[12 + q] * x[b * NQ + q];  // L1 RX half
        float hy = 0.5f * th[2 * q];                   // L0 RY half
        float hz = 0.5f * th[2 * q + 1];               // L0 RZ half
        float ca, sa, cy, sy, cz, sz;
        __sincosf(ha, &sa, &ca);
        __sincosf(hy, &sy, &cy);
        __sincosf(hz, &sz, &cz);
        // M = RX(a) RZ(z) RY(y) in SU(2): alpha = M00, beta = M10 (R9-verified)
        float ax = ca*cy*cz + sa*sy*sz;
        float ay = -(ca*cy*sz + sa*sy*cz);
        float bx = ca*sy*cz - sa*cy*sz;
        float by = ca*sy*sz - sa*cy*cz;
        gmA[q] = (v2f){ax, ay};
        gmB[q] = (v2f){bx, by};
    }
    __syncthreads();                                   // B1

    // ---- hoist ALL gate constants into registers and PIN them (R23) ----
    v2f GA[12], GB[12], GY[12];
#pragma unroll
    for (int q = 0; q < 12; ++q) {
        GA[q] = gmA[q];  PIN(GA[q]);
        GB[q] = gmB[q];  PIN(GB[q]);
        GY[q] = gyS[q];  PIN(GY[q]);
    }

    v2f v[16];

    // ---- init in layout C: L0 RX product state, ring0 folded ----
    // (R10-verified) i = P^{-1}(j), j = (t<<4)|r:
    //  i0=r0^r1 (q11), i1=r1^r2 (q10), i2=r2^r3 (q9), i3=r3^t0 (q8),
    //  i4..i9 = gray(t) bits 0..5 (qubits 7..2),
    //  i10 = t6^r0^t7 (q1), i11 = r0^t7 (q0)
    {
        const int g = (t ^ (t >> 1)) & 0x3F;
        float Pt = 1.0f;
#pragma unroll
        for (int m = 0; m < 6; ++m) {
            v2f cs = coI[7 - m];
            Pt *= ((g >> m) & 1) ? cs.y : cs.x;
        }
        const int ct = __popc(g);
        const int t0 = t & 1, t7 = (t >> 7) & 1;
        const int e1 = ((t >> 6) ^ (t >> 7)) & 1;
        v2f q11 = coI[11], q10 = coI[10], q9 = coI[9],
            q8 = coI[8], q1 = coI[1], q0 = coI[0];
        const float u8  = t0 ? q8.y : q8.x;     // qubit 8, key t0^r3
        const float u8n = t0 ? q8.x : q8.y;
        const float u1  = e1 ? q1.y : q1.x;     // qubit 1, key e1^r0
        const float u1n = e1 ? q1.x : q1.y;
        const float u0  = t7 ? q0.y : q0.x;     // qubit 0, key t7^r0
        const float u0n = t7 ? q0.x : q0.y;
#pragma unroll
        for (int r = 0; r < 16; ++r) {
            const int r0 = r & 1, r1 = (r >> 1) & 1, r2 = (r >> 2) & 1,
                      r3 = (r >> 3) & 1;
            const int b11 = r0 ^ r1, b10 = r1 ^ r2, b9 = r2 ^ r3;
            float m = Pt * (b11 ? q11.y : q11.x) * (b10 ? q10.y : q10.x)
                         * (b9 ? q9.y : q9.x) * (r3 ? u8n : u8)
                         * (r0 ? u1n : u1) * (r0 ? u0n : u0);
            int k = (ct + b11 + b10 + b9 + (r3 ^ t0) + (r0 ^ e1) + (r0 ^ t7)) & 3;
            v[r].x = (k == 0) ? m : ((k == 2) ? -m : 0.0f);
            v[r].y = (k == 3) ? m : ((k == 1) ? -m : 0.0f);
        }
    }

    // ---- fused M-pass (L0 RY,RZ + L1 RX), C -> B -> A ----
    M_PHASE(8);                       // qubits 8..11 in C
    LOCAL_X(ADDR_C, ADDR_B);          // X1: wave-local
    M_PHASE(4);                       // qubits 4..7  in B
#pragma unroll
    for (int r = 0; r < 16; ++r) S[ADDR_B(r)] = v[r];
    __syncthreads();                  // B2 (cross B -> A)
#pragma unroll
    for (int r = 0; r < 16; ++r) v[r] = S[ADDR_A(r)];
    M_PHASE(0);                       // qubits 0..3  in A

    // ---- layer-1 CNOT ring: A -> A (addr = Ft ^ const-folded G(r<<8)) ----
    __syncthreads();                  // B3 (all A-reads done before scatter)
#pragma unroll
    for (int r = 0; r < 16; ++r) {
        const int jr = r << 8;
        int yr = jr ^ (jr >> 1); yr ^= yr >> 2; yr ^= yr >> 4; yr ^= yr >> 8;
        const int pr = (yr & 0x7FF) | (((__popc(jr) ^ (jr >> 11)) & 1) << 11);
        const int Gr = (pr & ~15) | ((pr ^ (pr >> 4) ^ (pr >> 8)) & 15);
        S[Ft ^ Gr] = v[r];
    }
    __syncthreads();                  // B4
#pragma unroll
    for (int r = 0; r < 16; ++r) v[r] = S[ADDR_A(r)];

    // ---- layer-1 RY (final RZ dropped), A -> B -> C ----
    RY_PHASE(0);                      // in A
    // no barrier: store hits exactly the addresses THIS thread read at the
    // B4 gather; no other thread touches these slots (R2-verified).
#pragma unroll
    for (int r = 0; r < 16; ++r) S[ADDR_A(r)] = v[r];
    __syncthreads();                  // B5 (cross A -> B)
#pragma unroll
    for (int r = 0; r < 16; ++r) v[r] = S[ADDR_B(r)];
    RY_PHASE(4);                      // in B
    LOCAL_X(ADDR_B, ADDR_C);          // X5: wave-local
    RY_PHASE(8);                      // in C

    // ---- measurement in C ----
    // qubits 8..11 <-> r bits 3..0 ; qubits 2..7 <-> lane bits 5..0
    // (lane bit k = j[4+k] = qubit 7-k) ; qubits 0,1 <-> wave bits 1,0
    float p[16];
#pragma unroll
    for (int r = 0; r < 16; ++r)
        p[r] = fmaf(v[r].x, v[r].x, v[r].y * v[r].y);
    float sA[8], dA[8];
#pragma unroll
    for (int k = 0; k < 8; ++k) {
        sA[k] = p[2 * k] + p[2 * k + 1];
        dA[k] = p[2 * k] - p[2 * k + 1];
    }
    float z11 = ((dA[0] + dA[1]) + (dA[2] + dA[3]))
              + ((dA[4] + dA[5]) + (dA[6] + dA[7]));
    float sC[4], dC[4];
#pragma unroll
    for (int k = 0; k < 4; ++k) {
        sC[k] = sA[2 * k] + sA[2 * k + 1];
        dC[k] = sA[2 * k] - sA[2 * k + 1];
    }
    float z10 = (dC[0] + dC[1]) + (dC[2] + dC[3]);
    float e0 = sC[0] + sC[1], f0 = sC[0] - sC[1];
    float e1s = sC[2] + sC[3], f1 = sC[2] - sC[3];
    float vals[5];
    vals[0] = e0 + e1s;               // ptot
    vals[1] = e0 - e1s;               // z8  (r bit3)
    vals[2] = f0 + f1;                // z9  (r bit2)
    vals[3] = z10;                    // z10 (r bit1)
    vals[4] = z11;                    // z11 (r bit0)

    // 6-stage WHT butterfly: lane L ends with sum_l (-1)^{popc(L&l)} x_l
#pragma unroll
    for (int k = 0; k < 6; ++k) {
        const float sgn = ((l >> k) & 1) ? -1.f : 1.f;
#pragma unroll
        for (int m = 0; m < 5; ++m) {
            float tmp = __shfl_xor(vals[m], 1 << k, 64);
            vals[m] = fmaf(sgn, vals[m], tmp);
        }
    }
    if (l == 0) {                     // wave totals
        red[w * 12 + 0]  = vals[0];   // ptot (for qubits 0,1)
        red[w * 12 + 8]  = vals[1];
        red[w * 12 + 9]  = vals[2];
        red[w * 12 + 10] = vals[3];
        red[w * 12 + 11] = vals[4];
    } else if (__popc(l) == 1) {      // lane-bit sums: qubits 2..7
        int q = 8 - __ffs(l);         // l=1<<k -> q = 7-k
        red[w * 12 + q] = vals[0];
    }
    __syncthreads();                  // B6
    if (t < NQ) {
        float acc = 0.f;
#pragma unroll
        for (int ww = 0; ww < 4; ++ww) {
            if (t < 2) {
                float pv = red[ww * 12 + 0];
                acc += ((ww >> (1 - t)) & 1) ? -pv : pv;
            } else {
                acc += red[ww * 12 + t];
            }
        }
        out[b * NQ + t] = acc;
    }
}

extern "C" void kernel_launch(void* const* d_in, const int* in_sizes, int n_in,
                              void* d_out, int out_size, void* d_ws, size_t ws_size,
                              hipStream_t stream) {
    const int B = in_sizes[0] / NQ;  // 1024
    vqc_kernel<<<B, TPB, 0, stream>>>((const float*)d_in[0],
                                      (const float*)d_in[1],
                                      (const float*)d_in[2],
                                      (float*)d_out);
}

// Round 17
// 72.678 us; speedup vs baseline: 1.9244x; 1.0130x over previous
//
#include <hip/hip_runtime.h>
#include <math.h>

#define NQ 12
#define TPB 256

// R27 = R23 VERBATIM (final revert-to-best). Session conclusion: total =
// 39.6us harness fill (85% HBM roofline, untouchable) + ~33us kernel whose
// floor survived 16 falsification attempts across every programmable axis
// (op count, DS work, barriers, TLP, code size, pipelining, encoding,
// stagger, residency). R23 = best verified: 72.28us, absmax 9.8e-4.
//
// Amp index j (12 bits), qubit q <-> j bit 11-q. Register layouts
// (t = thread 0..255 gives 8 bits, r = reg index 4 bits):
//   A: j = (r<<8)|t                  r = j[11:8] = qubits 0..3
//   B: j = (t[7:4]<<8)|(r<<4)|t[3:0] r = j[7:4]  = qubits 4..7
//   C: j = (t<<4)|r                  r = j[3:0]  = qubits 8..11
// B,C share wave bits j[11:10] -> B<->C roundtrips wave-local.
// Swizzle sg(j) = (j&~15)|((j^(j>>4)^(j>>8))&15); with kC=(t^(t>>4))&15:
//   sg(J_A(r)) = VA ^ 257r,  VA = (t&0xF0)|kC
//   sg(J_B(r)) = VB ^ 17r,   VB = ((t>>4)<<8)|kC
//   sg(J_C(r)) = VC ^ r,     VC = (t<<4)|kC
//   sg(P(j))   = Ft ^ G(r<<8), Ft per-thread, G const-folded
//
// Gate algebra (SU(2) [[a,-conj b],[b,conj a]], a=(ax,ay), b=(bx,by),
// A2=(ax,ay), B2=(bx,by) packed; per-term word-select, R19-verified):
//  n0 = a*v0 - conj(b)*v1 ; n1 = b*v0 + conj(a)*v1
//  RY (Y2=(c,s)): n0 = c*v0 - s*v1 ; n1 = s*v0 + c*v1
//
// Circuit (algebra verified R2-R10): init(C) = L0 RX product state with
// ring0 FOLDED via inverse perm; fused M_q = RX(L1)*RZ(L0)*RY(L0); ring1
// scatter; L1 RY (final RZ dropped); <Z_q> via partial reg-WHT + 6-stage
// lane-WHT butterfly.

#define PKMUL(d, a, b, MODS)                                          \
    asm("v_pk_mul_f32 %0, %1, %2 " MODS                               \
        : "=v"(d) : "v"(a), "v"(b))
#define PKFMA(d, a, b, c, MODS)                                       \
    asm("v_pk_fma_f32 %0, %1, %2, %3 " MODS                           \
        : "=v"(d) : "v"(a), "v"(b), "v"(c))

// opaque register pin: severs the value's link to its LDS source so the
// compiler cannot rematerialize-by-reload; forces VGPR residency.
#define PIN(f2) asm("" : "+v"(f2))

// variadic: commas inside the body are re-joined by __VA_ARGS__
#define FOR_PAIRS4(RB, ...) do {                                      \
    const int msk_ = 1 << (RB);                                       \
    _Pragma("unroll")                                                 \
    for (int h_ = 0; h_ < 8; ++h_) {                                  \
        const int i0 = ((h_ & ~(msk_ - 1)) << 1) | (h_ & (msk_ - 1)); \
        const int i1 = i0 | msk_;                                     \
        __VA_ARGS__;                                                  \
    } } while (0)

// strength-reduced swizzled addresses (VA/VB/VC in scope)
#define ADDR_A(r) (VA ^ (257 * (r)))
#define ADDR_B(r) (VB ^ (17 * (r)))
#define ADDR_C(r) (VC ^ (r))

// compiler-only fence for the barrier-less wave-local store->load aliasing
#define CFENCE asm volatile("" ::: "memory")

// wave-local roundtrip (same-wave LDS ordering, no barrier)
#define LOCAL_X(AS, AD) do {                                          \
    _Pragma("unroll")                                                 \
    for (int r_ = 0; r_ < 16; ++r_) S[AS(r_)] = v[r_];                \
    CFENCE;                                                           \
    _Pragma("unroll")                                                 \
    for (int r_ = 0; r_ < 16; ++r_) v[r_] = S[AD(r_)];                \
  } while (0)

// SU(2) gate from register-resident packed constants (R19-verified MODS)
#define M_GATE(q, RB) do {                                                  \
        const float2 A2 = GA[q];                                            \
        const float2 B2 = GB[q];                                            \
        FOR_PAIRS4(RB,                                                      \
            const float2 a0 = v[i0];                                        \
            const float2 a1 = v[i1];                                        \
            float2 t, u;                                                    \
            PKMUL(t, a0, A2, "op_sel_hi:[1,0]");                            \
            PKFMA(t, a0, A2, t,                                             \
                  "op_sel:[1,1,0] op_sel_hi:[0,1,1] neg_lo:[0,1,0]");       \
            PKFMA(t, a1, B2, t,                                             \
                  "op_sel_hi:[1,0,1] neg_lo:[0,1,0] neg_hi:[0,1,0]");       \
            PKFMA(t, a1, B2, t,                                             \
                  "op_sel:[1,1,0] op_sel_hi:[0,1,1] neg_lo:[0,1,0]");       \
            PKMUL(u, a0, B2, "op_sel_hi:[1,0]");                            \
            PKFMA(u, a0, B2, u,                                             \
                  "op_sel:[1,1,0] op_sel_hi:[0,1,1] neg_lo:[0,1,0]");       \
            PKFMA(u, a1, A2, u, "op_sel_hi:[1,0,1]");                       \
            PKFMA(u, a1, A2, u,                                             \
                  "op_sel:[1,1,0] op_sel_hi:[0,1,1] neg_hi:[0,1,0]");       \
            v[i0] = t; v[i1] = u;                                           \
        );                                                                  \
    } while (0)

#define RY_GATE(q, RB) do {                                                 \
        const float2 Y2 = GY[q];                                            \
        FOR_PAIRS4(RB,                                                      \
            float2 t, u;                                                    \
            PKMUL(t, v[i0], Y2, "op_sel_hi:[1,0]");                         \
            PKFMA(t, v[i1], Y2, t,                                          \
                  "op_sel:[0,1,0] op_sel_hi:[1,1,1] "                       \
                  "neg_lo:[0,1,0] neg_hi:[0,1,0]");                         \
            PKMUL(u, v[i0], Y2, "op_sel:[0,1] op_sel_hi:[1,1]");            \
            PKFMA(u, v[i1], Y2, u, "op_sel_hi:[1,0,1]");                    \
            v[i0] = t; v[i1] = u;                                           \
        );                                                                  \
    } while (0)

// phase: gate qubit QB+d on r-bit 3-d (holds for A, B, C alike)
#define M_PHASE(QB)  do { _Pragma("unroll")                                 \
    for (int d_ = 0; d_ < 4; ++d_) M_GATE((QB) + d_, 3 - d_); } while (0)
#define RY_PHASE(QB) do { _Pragma("unroll")                                 \
    for (int d_ = 0; d_ < 4; ++d_) RY_GATE((QB) + d_, 3 - d_); } while (0)

__global__ __launch_bounds__(TPB, 2) void vqc_kernel(
    const float* __restrict__ x,    // [B, 12]
    const float* __restrict__ th,   // [2, 12, 2]
    const float* __restrict__ lm,   // [2, 12]
    float* __restrict__ out)        // [B, 12]
{
    __shared__ float2 S[4096];
    __shared__ float2 gmA[12];      // fused M gate: (ax, ay)
    __shared__ float2 gmB[12];      // fused M gate: (bx, by)
    __shared__ float2 gyS[12];      // L1 RY: (c, s)
    __shared__ float2 coI[12];      // L0 RX half-angle (c,s)
    __shared__ float red[4 * 12];

    const int b = blockIdx.x;
    const int t = threadIdx.x;
    const int l = t & 63;
    const int w = t >> 6;

    // strength-reduced address bases
    const int kC = (t ^ (t >> 4)) & 15;
    const int VA = (t & 0xF0) | kC;
    const int VB = ((t >> 4) << 8) | kC;
    const int VC = (t << 4) | kC;
    // ring per-thread part: Ft = sg(P-image of t) (GF(2)-linear split)
    int Ft;
    {
        int yt = t ^ (t >> 1); yt ^= yt >> 2; yt ^= yt >> 4; yt ^= yt >> 8;
        int pt = (yt & 0x7FF) | ((__popc(t) & 1) << 11);
        Ft = (pt & ~15) | ((pt ^ (pt >> 4) ^ (pt >> 8)) & 15);
    }

    // ---- cooperative coefficient precompute ----
    if (t < 12) {
        float h = 0.5f * lm[t] * x[b * NQ + t];
        float c, s; __sincosf(h, &s, &c);
        coI[t] = make_float2(c, s);
    } else if (t < 24) {
        int q = t - 12;
        float h = 0.5f * th[24 + 2 * q];
        float c, s; __sincosf(h, &s, &c);
        gyS[q] = make_float2(c, s);
    } else if (t < 36) {
        int q = t - 24;
        float ha = 0.5f * lm[12 + q] * x[b * NQ + q];  // L1 RX half
        float hy = 0.5f * th[2 * q];                   // L0 RY half
        float hz = 0.5f * th[2 * q + 1];               // L0 RZ half
        float ca, sa, cy, sy, cz, sz;
        __sincosf(ha, &sa, &ca);
        __sincosf(hy, &sy, &cy);
        __sincosf(hz, &sz, &cz);
        // M = RX(a) RZ(z) RY(y) in SU(2): alpha = M00, beta = M10 (R9-verified)
        float ax = ca*cy*cz + sa*sy*sz;
        float ay = -(ca*cy*sz + sa*sy*cz);
        float bx = ca*sy*cz - sa*cy*sz;
        float by = ca*sy*sz - sa*cy*cz;
        gmA[q] = make_float2(ax, ay);
        gmB[q] = make_float2(bx, by);
    }
    __syncthreads();                                   // B1

    // ---- hoist ALL gate constants into registers and PIN them ----
    float2 GA[12], GB[12], GY[12];
#pragma unroll
    for (int q = 0; q < 12; ++q) {
        GA[q] = gmA[q];  PIN(GA[q]);
        GB[q] = gmB[q];  PIN(GB[q]);
        GY[q] = gyS[q];  PIN(GY[q]);
    }

    float2 v[16];

    // ---- init in layout C: L0 RX product state, ring0 folded ----
    // (R10-verified) i = P^{-1}(j), j = (t<<4)|r:
    //  i0=r0^r1 (q11), i1=r1^r2 (q10), i2=r2^r3 (q9), i3=r3^t0 (q8),
    //  i4..i9 = gray(t) bits 0..5 (qubits 7..2),
    //  i10 = t6^r0^t7 (q1), i11 = r0^t7 (q0)
    {
        const int g = (t ^ (t >> 1)) & 0x3F;
        float Pt = 1.0f;
#pragma unroll
        for (int m = 0; m < 6; ++m) {
            float2 cs = coI[7 - m];
            Pt *= ((g >> m) & 1) ? cs.y : cs.x;
        }
        const int ct = __popc(g);
        const int t0 = t & 1, t7 = (t >> 7) & 1;
        const int e1 = ((t >> 6) ^ (t >> 7)) & 1;
        float2 q11 = coI[11], q10 = coI[10], q9 = coI[9],
               q8 = coI[8], q1 = coI[1], q0 = coI[0];
        const float u8  = t0 ? q8.y : q8.x;     // qubit 8, key t0^r3
        const float u8n = t0 ? q8.x : q8.y;
        const float u1  = e1 ? q1.y : q1.x;     // qubit 1, key e1^r0
        const float u1n = e1 ? q1.x : q1.y;
        const float u0  = t7 ? q0.y : q0.x;     // qubit 0, key t7^r0
        const float u0n = t7 ? q0.x : q0.y;
#pragma unroll
        for (int r = 0; r < 16; ++r) {
            const int r0 = r & 1, r1 = (r >> 1) & 1, r2 = (r >> 2) & 1,
                      r3 = (r >> 3) & 1;
            const int b11 = r0 ^ r1, b10 = r1 ^ r2, b9 = r2 ^ r3;
            float m = Pt * (b11 ? q11.y : q11.x) * (b10 ? q10.y : q10.x)
                         * (b9 ? q9.y : q9.x) * (r3 ? u8n : u8)
                         * (r0 ? u1n : u1) * (r0 ? u0n : u0);
            int k = (ct + b11 + b10 + b9 + (r3 ^ t0) + (r0 ^ e1) + (r0 ^ t7)) & 3;
            v[r].x = (k == 0) ? m : ((k == 2) ? -m : 0.0f);
            v[r].y = (k == 3) ? m : ((k == 1) ? -m : 0.0f);
        }
    }

    // ---- fused M-pass (L0 RY,RZ + L1 RX), C -> B -> A ----
    M_PHASE(8);                       // qubits 8..11 in C
    LOCAL_X(ADDR_C, ADDR_B);          // X1: wave-local
    M_PHASE(4);                       // qubits 4..7  in B
#pragma unroll
    for (int r = 0; r < 16; ++r) S[ADDR_B(r)] = v[r];
    __syncthreads();                  // B2 (cross B -> A)
#pragma unroll
    for (int r = 0; r < 16; ++r) v[r] = S[ADDR_A(r)];
    M_PHASE(0);                       // qubits 0..3  in A

    // ---- layer-1 CNOT ring: A -> A (addr = Ft ^ const-folded G(r<<8)) ----
    __syncthreads();                  // B3 (all A-reads done before scatter)
#pragma unroll
    for (int r = 0; r < 16; ++r) {
        const int jr = r << 8;
        int yr = jr ^ (jr >> 1); yr ^= yr >> 2; yr ^= yr >> 4; yr ^= yr >> 8;
        const int pr = (yr & 0x7FF) | (((__popc(jr) ^ (jr >> 11)) & 1) << 11);
        const int Gr = (pr & ~15) | ((pr ^ (pr >> 4) ^ (pr >> 8)) & 15);
        S[Ft ^ Gr] = v[r];
    }
    __syncthreads();                  // B4
#pragma unroll
    for (int r = 0; r < 16; ++r) v[r] = S[ADDR_A(r)];

    // ---- layer-1 RY (final RZ dropped), A -> B -> C ----
    RY_PHASE(0);                      // in A
    // no barrier: store hits exactly the addresses THIS thread read at the
    // B4 gather; no other thread touches these slots (R2-verified).
#pragma unroll
    for (int r = 0; r < 16; ++r) S[ADDR_A(r)] = v[r];
    __syncthreads();                  // B5 (cross A -> B)
#pragma unroll
    for (int r = 0; r < 16; ++r) v[r] = S[ADDR_B(r)];
    RY_PHASE(4);                      // in B
    LOCAL_X(ADDR_B, ADDR_C);          // X5: wave-local
    RY_PHASE(8);                      // in C

    // ---- measurement in C ----
    // qubits 8..11 <-> r bits 3..0 ; qubits 2..7 <-> lane bits 5..0
    // (lane bit k = j[4+k] = qubit 7-k) ; qubits 0,1 <-> wave bits 1,0
    float p[16];
#pragma unroll
    for (int r = 0; r < 16; ++r)
        p[r] = fmaf(v[r].x, v[r].x, v[r].y * v[r].y);
    float sA[8], dA[8];
#pragma unroll
    for (int k = 0; k < 8; ++k) {
        sA[k] = p[2 * k] + p[2 * k + 1];
        dA[k] = p[2 * k] - p[2 * k + 1];
    }
    float z11 = ((dA[0] + dA[1]) + (dA[2] + dA[3]))
              + ((dA[4] + dA[5]) + (dA[6] + dA[7]));
    float sC[4], dC[4];
#pragma unroll
    for (int k = 0; k < 4; ++k) {
        sC[k] = sA[2 * k] + sA[2 * k + 1];
        dC[k] = sA[2 * k] - sA[2 * k + 1];
    }
    float z10 = (dC[0] + dC[1]) + (dC[2] + dC[3]);
    float e0 = sC[0] + sC[1], f0 = sC[0] - sC[1];
    float e1s = sC[2] + sC[3], f1 = sC[2] - sC[3];
    float vals[5];
    vals[0] = e0 + e1s;               // ptot
    vals[1] = e0 - e1s;               // z8  (r bit3)
    vals[2] = f0 + f1;                // z9  (r bit2)
    vals[3] = z10;                    // z10 (r bit1)
    vals[4] = z11;                    // z11 (r bit0)

    // 6-stage WHT butterfly: lane L ends with sum_l (-1)^{popc(L&l)} x_l
#pragma unroll
    for (int k = 0; k < 6; ++k) {
        const float sgn = ((l >> k) & 1) ? -1.f : 1.f;
#pragma unroll
        for (int m = 0; m < 5; ++m) {
            float tmp = __shfl_xor(vals[m], 1 << k, 64);
            vals[m] = fmaf(sgn, vals[m], tmp);
        }
    }
    if (l == 0) {                     // wave totals
        red[w * 12 + 0]  = vals[0];   // ptot (for qubits 0,1)
        red[w * 12 + 8]  = vals[1];
        red[w * 12 + 9]  = vals[2];
        red[w * 12 + 10] = vals[3];
        red[w * 12 + 11] = vals[4];
    } else if (__popc(l) == 1) {      // lane-bit sums: qubits 2..7
        int q = 8 - __ffs(l);         // l=1<<k -> q = 7-k
        red[w * 12 + q] = vals[0];
    }
    __syncthreads();                  // B6
    if (t < NQ) {
        float acc = 0.f;
#pragma unroll
        for (int ww = 0; ww < 4; ++ww) {
            if (t < 2) {
                float pv = red[ww * 12 + 0];
                acc += ((ww >> (1 - t)) & 1) ? -pv : pv;
            } else {
                acc += red[ww * 12 + t];
            }
        }
        out[b * NQ + t] = acc;
    }
}

extern "C" void kernel_launch(void* const* d_in, const int* in_sizes, int n_in,
                              void* d_out, int out_size, void* d_ws, size_t ws_size,
                              hipStream_t stream) {
    const int B = in_sizes[0] / NQ;  // 1024
    vqc_kernel<<<B, TPB, 0, stream>>>((const float*)d_in[0],
                                      (const float*)d_in[1],
                                      (const float*)d_in[2],
                                      (float*)d_out);
}